// Round 4
// baseline (134.550 us; speedup 1.0000x reference)
//
#include <hip/hip_runtime.h>

// CustomEmbedding: out[b,s,:] = (x<1000) ? powers(softsign((x-mean)/std)) : W[x]
// x: [32,4096] int32, W: [50257,512] f32, out: [32,4096,512] f32 (268 MB).
//
// Round-4 theory: at 82 us we were at the HBM roofline for 536 MB of traffic
// (268 MB write + 268 MB gather-read). The 268 MB output write stream evicts
// W from the 256 MB Infinity Cache every replay, so gathers miss to HBM.
// Fix: bucket tokens by id-range (128 W rows = 256 KB per bucket) so every
// use of a W row happens within one short window while the slice is
// L2/L3-resident -> HBM read traffic drops from ~268 MB to ~100 MB.
// Pipeline: zero bucket counters -> histogram-scatter token indices ->
// bucketed gather kernel. Slot order within a bucket is atomic-order
// nondeterministic, but each token writes only its own output row, so the
// output is deterministic.

#define VOCAB 50257
#define NUM_COUNT 1000
#define NB ((VOCAB + 127) >> 7)      // 393 buckets of 128 ids (256 KB of W)
#define CAP 640                      // slots per bucket (mean 334, >15 sigma)
#define TOK_PER_BLOCK 8
#define BUCKET_BLOCKS (CAP / TOK_PER_BLOCK)   // 80

typedef float f32x4 __attribute__((ext_vector_type(4)));

__device__ __forceinline__ f32x4 num_powers(int id, int lane) {
    // mean = 499.5 ; std = sqrt(83333.25) + 1e-6
    const float kMean = 499.5f;
    const float kInvStd = 1.0f / 288.67499125725f;
    float n = ((float)id - kMean) * kInvStd;
    float s = n / (1.0f + fabsf(n));                   // softsign, |s| <= 0.634
    float a = fabsf(s);
    float l = log2f(a);
    int e0 = (lane << 2) + 1;                          // first exponent (odd)
    float m = exp2f((float)e0 * l);                    // |s|^e0
    float p0 = (s < 0.0f) ? -m : m;                    // e0 odd -> sign(s)
    float p1 = p0 * s;
    float p2 = p1 * s;
    float p3 = p2 * s;
    f32x4 r = {p0, p1, p2, p3};
    return r;
}

__global__ void zero_counts_kernel(int* __restrict__ cnt) {
    for (int i = threadIdx.x; i < NB; i += blockDim.x) cnt[i] = 0;
}

__global__ __launch_bounds__(256) void hist_kernel(
    const int* __restrict__ x, int* __restrict__ cnt, int* __restrict__ idx,
    int n_tokens) {
    int t = blockIdx.x * blockDim.x + threadIdx.x;
    if (t >= n_tokens) return;
    int id = x[t];
    int b = id >> 7;
    int pos = atomicAdd(&cnt[b], 1);
    if (pos < CAP) idx[b * CAP + pos] = t;
}

__global__ __launch_bounds__(256) void gather_kernel(
    const int* __restrict__ x, const float* __restrict__ W,
    const int* __restrict__ cnt, const int* __restrict__ idx,
    float* __restrict__ out) {
    unsigned int b  = blockIdx.x / BUCKET_BLOCKS;
    unsigned int bb = blockIdx.x % BUCKET_BLOCKS;
    int c = cnt[b];                       // scalar (wave-uniform) load
    if (c > CAP) c = CAP;
    int base = bb * TOK_PER_BLOCK;
    if (base >= c) return;

    int h    = threadIdx.x >> 7;          // 0 or 1
    int lane = threadIdx.x & 127;
    const int* bidx = &idx[b * CAP];

    // 4 slots per thread: s = base + h + 2k, k=0..3
    int s0 = base + h;
    int s1 = s0 + 2, s2 = s0 + 4, s3 = s0 + 6;
    bool v0 = s0 < c, v1 = s1 < c, v2 = s2 < c, v3 = s3 < c;
    int cm1 = c - 1;
    int t0 = bidx[v0 ? s0 : cm1];
    int t1 = bidx[v1 ? s1 : cm1];
    int t2 = bidx[v2 ? s2 : cm1];
    int t3 = bidx[v3 ? s3 : cm1];

    int id0 = x[t0], id1 = x[t1], id2 = x[t2], id3 = x[t3];

    const f32x4* Wv = reinterpret_cast<const f32x4*>(W);
    // 4 independent gathers in flight (bucket slice is L2-resident)
    f32x4 r0 = Wv[(size_t)id0 * 128 + lane];
    f32x4 r1 = Wv[(size_t)id1 * 128 + lane];
    f32x4 r2 = Wv[(size_t)id2 * 128 + lane];
    f32x4 r3 = Wv[(size_t)id3 * 128 + lane];

    if (id0 < NUM_COUNT) r0 = num_powers(id0, lane);
    if (id1 < NUM_COUNT) r1 = num_powers(id1, lane);
    if (id2 < NUM_COUNT) r2 = num_powers(id2, lane);
    if (id3 < NUM_COUNT) r3 = num_powers(id3, lane);

    f32x4* outv = reinterpret_cast<f32x4*>(out);
    if (v0) __builtin_nontemporal_store(r0, &outv[(size_t)t0 * 128 + lane]);
    if (v1) __builtin_nontemporal_store(r1, &outv[(size_t)t1 * 128 + lane]);
    if (v2) __builtin_nontemporal_store(r2, &outv[(size_t)t2 * 128 + lane]);
    if (v3) __builtin_nontemporal_store(r3, &outv[(size_t)t3 * 128 + lane]);
}

// ---- fallback (round-3 kernel) if ws is too small for the bucket arrays ----
__global__ __launch_bounds__(256) void direct_kernel(
    const int* __restrict__ x, const float* __restrict__ W,
    float* __restrict__ out, int n_groups) {
    int gid = blockIdx.x * blockDim.x + threadIdx.x;
    int g    = gid >> 7;
    int lane = gid & 127;
    if (g >= n_groups) return;
    int4 ids = reinterpret_cast<const int4*>(x)[g];
    const f32x4* Wv = reinterpret_cast<const f32x4*>(W);
    f32x4 v0 = Wv[(size_t)ids.x * 128 + lane];
    f32x4 v1 = Wv[(size_t)ids.y * 128 + lane];
    f32x4 v2 = Wv[(size_t)ids.z * 128 + lane];
    f32x4 v3 = Wv[(size_t)ids.w * 128 + lane];
    if (ids.x < NUM_COUNT) v0 = num_powers(ids.x, lane);
    if (ids.y < NUM_COUNT) v1 = num_powers(ids.y, lane);
    if (ids.z < NUM_COUNT) v2 = num_powers(ids.z, lane);
    if (ids.w < NUM_COUNT) v3 = num_powers(ids.w, lane);
    f32x4* outv = reinterpret_cast<f32x4*>(out);
    size_t base = (size_t)g * 512 + lane;
    __builtin_nontemporal_store(v0, &outv[base]);
    __builtin_nontemporal_store(v1, &outv[base + 128]);
    __builtin_nontemporal_store(v2, &outv[base + 256]);
    __builtin_nontemporal_store(v3, &outv[base + 384]);
}

extern "C" void kernel_launch(void* const* d_in, const int* in_sizes, int n_in,
                              void* d_out, int out_size, void* d_ws, size_t ws_size,
                              hipStream_t stream) {
    const int*   x = (const int*)d_in[0];
    const float* W = (const float*)d_in[1];
    float*     out = (float*)d_out;
    int n_tokens = in_sizes[0];                        // 131072

    size_t need = (size_t)NB * 4 + (size_t)NB * CAP * 4;   // ~1.01 MB
    if (ws_size >= need && (n_tokens % 4) == 0) {
        int* cnt = (int*)d_ws;
        int* idx = cnt + NB;
        zero_counts_kernel<<<1, 512, 0, stream>>>(cnt);
        hist_kernel<<<(n_tokens + 255) / 256, 256, 0, stream>>>(x, cnt, idx, n_tokens);
        gather_kernel<<<NB * BUCKET_BLOCKS, 256, 0, stream>>>(x, W, cnt, idx, out);
    } else {
        int n_groups = n_tokens / 4;
        long long total_threads = (long long)n_groups * 128;
        int grid = (int)((total_threads + 255) / 256);
        direct_kernel<<<grid, 256, 0, stream>>>(x, W, out, n_groups);
    }
}

// Round 5
// 80.680 us; speedup vs baseline: 1.6677x; 1.6677x over previous
//
#include <hip/hip_runtime.h>

// CustomEmbedding: out[b,s,:] = (x<1000) ? powers(softsign((x-mean)/std)) : W[x]
// x: [32,4096] int32, W: [50257,512] f32, out: [32,4096,512] f32 (268 MB).
//
// Round-5: revert round-4's bucketing (scattered 2KB output writes destroyed
// the sequential write stream: 82 -> 134 us). Keep round-3 structure
// (4 tokens/thread, 4 gathers in flight, sequential writes) and attack the
// read traffic instead: emit output stores as inline-asm
// `global_store_dwordx4 ... sc0 sc1 nt` (strongest streaming/no-allocate
// policy on gfx950) so the 268 MB write stream does not cycle the 256 MB
// Infinity Cache and W (103 MB) stays MALL-resident across graph replays.

#define NUM_COUNT 1000
#define TOK_PER_THREAD 4

typedef float f32x4 __attribute__((ext_vector_type(4)));

__device__ __forceinline__ void stream_store(f32x4* p, f32x4 v) {
    asm volatile("global_store_dwordx4 %0, %1, off sc0 sc1 nt"
                 :: "v"(p), "v"(v) : "memory");
}

__device__ __forceinline__ f32x4 num_powers(int id, int lane) {
    // mean = 499.5 ; std = sqrt(83333.25) + 1e-6
    const float kMean = 499.5f;
    const float kInvStd = 1.0f / 288.67499125725f;
    float n = ((float)id - kMean) * kInvStd;
    float s = n / (1.0f + fabsf(n));                   // softsign, |s| <= 0.634
    float a = fabsf(s);
    float l = log2f(a);
    int e0 = (lane << 2) + 1;                          // first exponent (odd)
    float m = exp2f((float)e0 * l);                    // |s|^e0
    float p0 = (s < 0.0f) ? -m : m;                    // e0 odd -> sign(s)
    float p1 = p0 * s;
    float p2 = p1 * s;
    float p3 = p2 * s;
    f32x4 r = {p0, p1, p2, p3};
    return r;
}

__global__ __launch_bounds__(256) void custom_embedding_kernel(
    const int* __restrict__ x, const float* __restrict__ W,
    float* __restrict__ out, int n_groups) {
    int gid = blockIdx.x * blockDim.x + threadIdx.x;
    int g    = gid >> 7;        // token-group (4 tokens), 128 lanes each
    int lane = gid & 127;
    if (g >= n_groups) return;

    int4 ids = reinterpret_cast<const int4*>(x)[g];    // tokens 4g..4g+3 (bcast)

    const f32x4* Wv = reinterpret_cast<const f32x4*>(W);
    // 4 independent gathers in flight before any use
    f32x4 v0 = Wv[(size_t)ids.x * 128 + lane];
    f32x4 v1 = Wv[(size_t)ids.y * 128 + lane];
    f32x4 v2 = Wv[(size_t)ids.z * 128 + lane];
    f32x4 v3 = Wv[(size_t)ids.w * 128 + lane];

    // rare (~2%) wave-uniform overwrites for numeric tokens
    if (ids.x < NUM_COUNT) v0 = num_powers(ids.x, lane);
    if (ids.y < NUM_COUNT) v1 = num_powers(ids.y, lane);
    if (ids.z < NUM_COUNT) v2 = num_powers(ids.z, lane);
    if (ids.w < NUM_COUNT) v3 = num_powers(ids.w, lane);

    f32x4* outv = reinterpret_cast<f32x4*>(out);
    size_t base = (size_t)g * (TOK_PER_THREAD * 128) + lane;
    stream_store(&outv[base],       v0);
    stream_store(&outv[base + 128], v1);
    stream_store(&outv[base + 256], v2);
    stream_store(&outv[base + 384], v3);
}

extern "C" void kernel_launch(void* const* d_in, const int* in_sizes, int n_in,
                              void* d_out, int out_size, void* d_ws, size_t ws_size,
                              hipStream_t stream) {
    const int*   x = (const int*)d_in[0];
    const float* W = (const float*)d_in[1];
    float*     out = (float*)d_out;
    int n_tokens = in_sizes[0];                        // 131072
    int n_groups = n_tokens / TOK_PER_THREAD;          // 32768 (divisible)

    long long total_threads = (long long)n_groups * 128;
    int block = 256;
    int grid = (int)((total_threads + block - 1) / block);
    custom_embedding_kernel<<<grid, block, 0, stream>>>(x, W, out, n_groups);
}